// Round 11
// baseline (522.197 us; speedup 1.0000x reference)
//
#include <hip/hip_runtime.h>
#include <hip/hip_bf16.h>
#include <stdint.h>

// fSRN: fused SIREN + 3 forward-mode tangent streams, MFMA engine, v11.
// v11 = v10 (VERIFIED: 295 us kernel, absmax 0.015625) + ONE isolated change:
//   __launch_bounds__(512, 6)  (was (512,4)).
//   v10 post-mortem: occupancy stuck at 44% because the (512,4) bound caps
//   the unified register file at 128/thread; allocator used 64 arch + 64 acc
//   -> exactly 4 waves/SIMD -> 2 WGs/CU. The (512,6) bound caps at ~85 total;
//   persistent state is mst(32) + acc(16) = 48, so ~85 should fit ->
//   6 waves/SIMD -> 3 WGs/CU (75% occupancy ceiling), 3 independent barrier
//   domains vs 2. Falsifier: spill returns (WRITE_SIZE >> 10 MB) -> revert.
//
// Structure (v8/v10): WG = 512 thr (8 waves), P_WG = 16 points.
// A = 64 rows (4 streams x 16 pts) x 128 cols bf16 in LDS, XOR-swizzled.
// W from L2: prep_w_kernel writes fragment-ordered bf16 image into d_ws;
// gemm loads W fragments directly (192 KB, L2-resident, coalesced).
// Wave (wm = wave>>2, wn = wave&3) computes rows [wm*32,+32) x cols
// [wn*32,+32): 2mt x 2nt x 4kk mfma 16x16x32.

#define OMEGA_C 30.0f

constexpr int NPTS = 131072;
constexpr int FDIM = 128;
constexpr int NBLK = 3;
constexpr int P_WG = 16;
constexpr int NTHR = 512;   // 8 waves

typedef short bf16x8 __attribute__((ext_vector_type(8)));
typedef float f32x4  __attribute__((ext_vector_type(4)));

__device__ __forceinline__ uint16_t f2bf(float f) {
    __hip_bfloat16 h = __float2bfloat16(f);     // HW RNE
    return __builtin_bit_cast(uint16_t, h);
}
__device__ __forceinline__ float bf2f(uint16_t u) {
    return __bfloat162float(__builtin_bit_cast(__hip_bfloat16, u));
}

// swizzled byte offset into a [rows][128] bf16 tile with 256 B rows:
// 16B chunk index XORed with (row & 15).
__device__ __forceinline__ int swz(int row, int col) {
    const int b = col << 1;
    return (row << 8) + ((((b >> 4) ^ (row & 15)) << 4) | (b & 15));
}

// ---- kernel 1: weights -> bf16 fragment image in ws ----
// tile t (0..5) = {w1[0], w2[0], 0.5*w1[1], w2[1], 0.5*w1[2], w2[2]}
// frag flat id = (t*4+wn)*512 + kk*128 + nt*64 + lane   (uint4 units)
// content: W[col][k0..k0+8), col = wn*32+nt*16+(lane&15), k0 = kk*32+(lane>>4)*8
__global__ void prep_w_kernel(const float* __restrict__ res_w1,
                              const float* __restrict__ res_w2,
                              uint4* __restrict__ ws) {
    const int t = blockIdx.x;
    const int b = t >> 1, l = t & 1;
    const float scale = (l == 0 && b > 0) ? 0.5f : 1.0f;
    const float* src = (l == 0 ? res_w1 : res_w2) + b * FDIM * FDIM;
    #pragma unroll
    for (int i = 0; i < 8; ++i) {
        const int g    = (int)threadIdx.x + (i << 8);   // 0..2047 within tile
        const int lane = g & 63;
        const int nt   = (g >> 6) & 1;
        const int kk   = (g >> 7) & 3;
        const int wn   = g >> 9;
        const int col  = wn*32 + nt*16 + (lane & 15);
        const int k0   = kk*32 + (lane >> 4) * 8;
        const float4 v0 = *reinterpret_cast<const float4*>(src + col*FDIM + k0);
        const float4 v1 = *reinterpret_cast<const float4*>(src + col*FDIM + k0 + 4);
        uint4 w;
        w.x = (uint32_t)f2bf(scale*v0.x) | ((uint32_t)f2bf(scale*v0.y) << 16);
        w.y = (uint32_t)f2bf(scale*v0.z) | ((uint32_t)f2bf(scale*v0.w) << 16);
        w.z = (uint32_t)f2bf(scale*v1.x) | ((uint32_t)f2bf(scale*v1.y) << 16);
        w.w = (uint32_t)f2bf(scale*v1.z) | ((uint32_t)f2bf(scale*v1.w) << 16);
        ws[t*2048 + g] = w;
    }
}

// ---- kernel 2: the fused network ----
__global__ __launch_bounds__(NTHR, 6) void fsrn_kernel(
    const float* __restrict__ coords,
    const float* __restrict__ first_w,
    const float* __restrict__ first_b,
    const float* __restrict__ res_b1,
    const float* __restrict__ res_b2,
    const float* __restrict__ final_w,
    const uint4* __restrict__ ws,
    float* __restrict__ out)
{
    __shared__ __align__(16) uint8_t A8[64 * 256];    // 16 KiB activations
    __shared__ __align__(16) uint8_t C8[16 * 256];    //  4 KiB OMEGA*cos
    __shared__ float xyz[P_WG * 3];                   // 192 B
    __shared__ float outp[3][4][P_WG][3];             // 2304 B

    const int tid  = threadIdx.x;
    const int wave = tid >> 6;
    const int lane = tid & 63;
    const int l15  = lane & 15;
    const int lq   = lane >> 4;            // 0..3
    const int wm   = wave >> 2;            // 0: rows 0..31 (h, dhx), 1: rows 32..63 (dhy, dhz)
    const int wn   = wave & 3;             // col quarter
    const int rowbase = wm * 32;
    const int colbase = wn * 32;
    const int pt0  = blockIdx.x * P_WG;

    float mst[2][2][4];    // fp32 masters [mt][nt][j] — static idx ONLY
    f32x4 acc[2][2];       // MFMA accumulators [mt][nt] — static idx ONLY

    if (tid < P_WG * 3) xyz[tid] = coords[pt0 * 3 + tid];
    __syncthreads();

    // ---- first layer ----
    #pragma unroll
    for (int mt = 0; mt < 2; ++mt) {
        const int s_mt = 2*wm + mt;          // stream of these 16 rows
        #pragma unroll
        for (int nt = 0; nt < 2; ++nt) {
            const int f = colbase + nt*16 + l15;
            const float w0 = first_w[f*3+0], w1 = first_w[f*3+1], w2 = first_w[f*3+2];
            const float fb = first_b[f];
            const float wk = (s_mt == 1) ? w0 : (s_mt == 2) ? w1 : w2;
            #pragma unroll
            for (int j = 0; j < 4; ++j) {
                const int p = lq*4 + j;
                const float pre = OMEGA_C * (xyz[p*3]*w0 + xyz[p*3+1]*w1 + xyz[p*3+2]*w2 + fb);
                const float v = (s_mt == 0) ? __sinf(pre) : OMEGA_C * __cosf(pre) * wk;
                mst[mt][nt][j] = v;
                *reinterpret_cast<uint16_t*>(A8 + swz(rowbase + mt*16 + p, f)) = f2bf(v);
            }
        }
    }
    __syncthreads();

    // GEMM vs W-tile t (fragments from L2)
    auto gemm = [&](int t) {
        #pragma unroll
        for (int mt = 0; mt < 2; ++mt)
            #pragma unroll
            for (int nt = 0; nt < 2; ++nt) acc[mt][nt] = f32x4{0.f,0.f,0.f,0.f};
        const uint4* wbase = ws + (t*4 + wn)*512 + lane;
        #pragma unroll
        for (int kk = 0; kk < 4; ++kk) {
            const uint4 wq0 = wbase[kk*128];
            const uint4 wq1 = wbase[kk*128 + 64];
            const bf16x8 wf0 = __builtin_bit_cast(bf16x8, wq0);
            const bf16x8 wf1 = __builtin_bit_cast(bf16x8, wq1);
            const bf16x8 af0 = *reinterpret_cast<const bf16x8*>(
                A8 + swz(rowbase + l15, kk*32 + lq*8));
            const bf16x8 af1 = *reinterpret_cast<const bf16x8*>(
                A8 + swz(rowbase + 16 + l15, kk*32 + lq*8));
            acc[0][0] = __builtin_amdgcn_mfma_f32_16x16x32_bf16(af0, wf0, acc[0][0], 0, 0, 0);
            acc[0][1] = __builtin_amdgcn_mfma_f32_16x16x32_bf16(af0, wf1, acc[0][1], 0, 0, 0);
            acc[1][0] = __builtin_amdgcn_mfma_f32_16x16x32_bf16(af1, wf0, acc[1][0], 0, 0, 0);
            acc[1][1] = __builtin_amdgcn_mfma_f32_16x16x32_bf16(af1, wf1, acc[1][1], 0, 0, 0);
        }
    };

    #pragma unroll 1
    for (int b = 0; b < NBLK; ++b) {
        // ================= sub-layer 1: W = s*w1[b] (tile 2b) =================
        gemm(2*b);
        if (wm == 0) {   // primal rows (mt 0): sincos; publish cos; stage sin in acc
            #pragma unroll
            for (int nt = 0; nt < 2; ++nt) {
                const int f = colbase + nt*16 + l15;
                const float ob = OMEGA_C * res_b1[b*FDIM + f];
                #pragma unroll
                for (int j = 0; j < 4; ++j) {
                    const int p = lq*4 + j;
                    const float pre = OMEGA_C * acc[0][nt][j] + ob;
                    float sv, cv;
                    __sincosf(pre, &sv, &cv);
                    *reinterpret_cast<uint16_t*>(C8 + swz(p, f)) = f2bf(OMEGA_C * cv);
                    acc[0][nt][j] = sv;
                }
            }
        }
        __syncthreads();   // gemm A8 reads done; C8 visible
        if (wm == 0) {
            #pragma unroll
            for (int nt = 0; nt < 2; ++nt) {
                const int f = colbase + nt*16 + l15;
                #pragma unroll
                for (int j = 0; j < 4; ++j) {
                    const int p = lq*4 + j;
                    *reinterpret_cast<uint16_t*>(A8 + swz(p, f)) = f2bf(acc[0][nt][j]);
                    const float cv = bf2f(*reinterpret_cast<const uint16_t*>(C8 + swz(p, f)));
                    *reinterpret_cast<uint16_t*>(A8 + swz(16 + p, f)) = f2bf(cv * acc[1][nt][j]);
                }
            }
        } else {
            #pragma unroll
            for (int mt = 0; mt < 2; ++mt)
                #pragma unroll
                for (int nt = 0; nt < 2; ++nt) {
                    const int f = colbase + nt*16 + l15;
                    #pragma unroll
                    for (int j = 0; j < 4; ++j) {
                        const int p = lq*4 + j;
                        const float cv = bf2f(*reinterpret_cast<const uint16_t*>(C8 + swz(p, f)));
                        *reinterpret_cast<uint16_t*>(A8 + swz(rowbase + mt*16 + p, f))
                            = f2bf(cv * acc[mt][nt][j]);
                    }
                }
        }
        __syncthreads();

        // ================= sub-layer 2: W = w2[b] (tile 2b+1), residual ======
        gemm(2*b + 1);
        if (wm == 0) {
            #pragma unroll
            for (int nt = 0; nt < 2; ++nt) {
                const int f = colbase + nt*16 + l15;
                const float ob = OMEGA_C * res_b2[b*FDIM + f];
                #pragma unroll
                for (int j = 0; j < 4; ++j) {
                    const int p = lq*4 + j;
                    const float pre = OMEGA_C * acc[0][nt][j] + ob;
                    float sv, cv;
                    __sincosf(pre, &sv, &cv);
                    *reinterpret_cast<uint16_t*>(C8 + swz(p, f)) = f2bf(OMEGA_C * cv);
                    mst[0][nt][j] += sv;
                    acc[0][nt][j] = mst[0][nt][j];
                }
            }
        }
        __syncthreads();
        if (wm == 0) {
            #pragma unroll
            for (int nt = 0; nt < 2; ++nt) {
                const int f = colbase + nt*16 + l15;
                #pragma unroll
                for (int j = 0; j < 4; ++j) {
                    const int p = lq*4 + j;
                    *reinterpret_cast<uint16_t*>(A8 + swz(p, f)) = f2bf(acc[0][nt][j]);
                    const float cv = bf2f(*reinterpret_cast<const uint16_t*>(C8 + swz(p, f)));
                    mst[1][nt][j] += cv * acc[1][nt][j];
                    *reinterpret_cast<uint16_t*>(A8 + swz(16 + p, f)) = f2bf(mst[1][nt][j]);
                }
            }
        } else {
            #pragma unroll
            for (int mt = 0; mt < 2; ++mt)
                #pragma unroll
                for (int nt = 0; nt < 2; ++nt) {
                    const int f = colbase + nt*16 + l15;
                    #pragma unroll
                    for (int j = 0; j < 4; ++j) {
                        const int p = lq*4 + j;
                        const float cv = bf2f(*reinterpret_cast<const uint16_t*>(C8 + swz(p, f)));
                        mst[mt][nt][j] += cv * acc[mt][nt][j];
                        *reinterpret_cast<uint16_t*>(A8 + swz(rowbase + mt*16 + p, f))
                            = f2bf(mst[mt][nt][j]);
                    }
                }
        }
        __syncthreads();
    }

    // ---- final: out[:,c] = signed combos of dh_k . final_w[row] ----
    // k=0: wr={0,3,2} sg={+,-,+}; k=1: wr={3,0,1} sg={+,+,-}; k=2: wr={2,1,0} sg={-,+,+}
    #pragma unroll
    for (int mt = 0; mt < 2; ++mt) {
        if (wm == 1 || mt == 1) {
            const int k = 2*wm + mt - 1;       // wave-uniform tangent index
            #pragma unroll
            for (int c = 0; c < 3; ++c) {
                int wr; float sg;
                if (c == 0)      { wr = (k==0)?0:(k==1)?3:2; sg = (k==2)?-1.f:1.f; }
                else if (c == 1) { wr = (k==0)?3:(k==1)?0:1; sg = (k==0)?-1.f:1.f; }
                else             { wr = (k==0)?2:(k==1)?1:0; sg = (k==1)?-1.f:1.f; }
                const float fw0 = final_w[wr*FDIM + colbase + l15];
                const float fw1 = final_w[wr*FDIM + colbase + 16 + l15];
                #pragma unroll
                for (int j = 0; j < 4; ++j) {
                    float part = mst[mt][0][j] * fw0 + mst[mt][1][j] * fw1;
                    part += __shfl_xor(part, 1);
                    part += __shfl_xor(part, 2);
                    part += __shfl_xor(part, 4);
                    part += __shfl_xor(part, 8);
                    if (l15 == 0) outp[k][wn][lq*4 + j][c] = sg * part;
                }
            }
        }
    }
    __syncthreads();

    if (tid < P_WG * 3) {
        const int p = tid / 3, c = tid % 3;
        float s = 0.f;
        #pragma unroll
        for (int k = 0; k < 3; ++k)
            #pragma unroll
            for (int q = 0; q < 4; ++q) s += outp[k][q][p][c];
        out[(pt0 + p)*3 + c] = s;
    }
}

extern "C" void kernel_launch(void* const* d_in, const int* in_sizes, int n_in,
                              void* d_out, int out_size, void* d_ws, size_t ws_size,
                              hipStream_t stream) {
    const float* coords  = (const float*)d_in[0];
    const float* first_w = (const float*)d_in[1];
    const float* first_b = (const float*)d_in[2];
    const float* res_w1  = (const float*)d_in[3];
    const float* res_b1  = (const float*)d_in[4];
    const float* res_w2  = (const float*)d_in[5];
    const float* res_b2  = (const float*)d_in[6];
    const float* final_w = (const float*)d_in[7];
    // final_b (d_in[8]) does not influence the Jacobian -> unused.
    uint4* ws = (uint4*)d_ws;   // 12288 x 16 B = 192 KiB fragment image

    prep_w_kernel<<<dim3(6), dim3(256), 0, stream>>>(res_w1, res_w2, ws);
    fsrn_kernel<<<dim3(NPTS / P_WG), dim3(NTHR), 0, stream>>>(
        coords, first_w, first_b, res_b1, res_b2, final_w, ws, (float*)d_out);
}